// Round 7
// baseline (4657.152 us; speedup 1.0000x reference)
//
#include <hip/hip_runtime.h>

#define HSZ 128
#define NEGRID 100

// ---------- float <-> order-preserving uint (for atomic float max) ----------
__device__ __forceinline__ unsigned encf(float f) {
  unsigned i = __float_as_uint(f);
  return (i & 0x80000000u) ? ~i : (i | 0x80000000u);
}
__device__ __forceinline__ float decf(unsigned u) {
  return (u & 0x80000000u) ? __uint_as_float(u & 0x7fffffffu) : __uint_as_float(~u);
}

// ---------- h = x@node_w + node_b ; e = edge_attr@edgep_w + edgep_b ----------
__global__ void k_embed(const float* __restrict__ x, const float* __restrict__ ea,
                        const float* __restrict__ nw, const float* __restrict__ nb,
                        const float* __restrict__ ew, const float* __restrict__ eb,
                        float* __restrict__ h, float* __restrict__ e,
                        float* __restrict__ smean, int N, int E) {
  int row = blockIdx.x, c = threadIdx.x;
  if (row == 0 && c < 16) smean[c] = 0.f;
  if (row < N) {
    float acc = nb[c];
#pragma unroll
    for (int k = 0; k < 4; ++k) acc += x[row * 4 + k] * nw[k * 128 + c];
    h[row * 128 + c] = acc;
  } else {
    int ei = row - N;
    float acc = eb[c];
#pragma unroll
    for (int k = 0; k < 5; ++k) acc += ea[ei * 5 + k] * ew[k * 128 + c];
    e[ei * 128 + c] = acc;
  }
}

// ---------- per layer: xl = h@W (nodes), s_src/s_dst per node; s_edge per edge ----------
__global__ void k_gat_lin(const float* __restrict__ h, const float* __restrict__ e,
                          const float* __restrict__ W, const float* __restrict__ We,
                          const float* __restrict__ asrc, const float* __restrict__ adst,
                          const float* __restrict__ aedge,
                          float* __restrict__ xl, float* __restrict__ ssrc,
                          float* __restrict__ sdst, float* __restrict__ sedge,
                          float* __restrict__ smean4, unsigned* __restrict__ menc,
                          float* __restrict__ den, float* __restrict__ outacc,
                          int N, int E) {
  __shared__ float row_lds[128];
  __shared__ float red[128];
  __shared__ float red2[128];
  int row = blockIdx.x, c = threadIdx.x;
  const float* M;
  if (row < N) { row_lds[c] = h[row * 128 + c]; M = W; }
  else         { row_lds[c] = e[(row - N) * 128 + c]; M = We; }
  __syncthreads();
  float acc = 0.f;
  for (int k = 0; k < 128; ++k) acc += row_lds[k] * M[k * 128 + c];
  if (row < N) {
    xl[row * 128 + c] = acc;
    outacc[row * 128 + c] = 0.f;
    if (c < 4) { menc[row * 4 + c] = 0u; den[row * 4 + c] = 0.f; }
    red[c]  = acc * asrc[c];
    red2[c] = acc * adst[c];
    __syncthreads();
    if (c < 8) {
      int hh = c & 3;
      const float* b = (c < 4) ? red : red2;
      float s = 0.f;
      for (int t = 0; t < 32; ++t) s += b[hh * 32 + t];
      if (c < 4) ssrc[row * 4 + hh] = s; else sdst[row * 4 + hh] = s;
    }
  } else {
    int ei = row - N;
    red[c] = acc * aedge[c];
    __syncthreads();
    if (c < 4) {
      float s = 0.f;
      for (int t = 0; t < 32; ++t) s += red[c * 32 + t];
      sedge[ei * 4 + c] = s;
      atomicAdd(&smean4[c], s);
    }
  }
}

// ---------- alpha (leaky-relu) + atomic segment max over dst ----------
__global__ void k_alpha(const float* __restrict__ ssrc, const float* __restrict__ sdst,
                        const float* __restrict__ sedge, const float* __restrict__ smean4,
                        const int* __restrict__ srcI, const int* __restrict__ dstI,
                        float* __restrict__ alpha, unsigned* __restrict__ menc,
                        int N, int E, float invE) {
  int gid = blockIdx.x * 256 + threadIdx.x;
  if (gid >= (E + N) * 4) return;
  int item = gid >> 2, hh = gid & 3;
  float a; int dnode;
  if (item < E) {
    a = ssrc[srcI[item] * 4 + hh] + sdst[dstI[item] * 4 + hh] + sedge[item * 4 + hh];
    dnode = dstI[item];
  } else {
    int n = item - E;
    a = ssrc[n * 4 + hh] + sdst[n * 4 + hh] + smean4[hh] * invE;
    dnode = n;
  }
  a = (a > 0.f) ? a : 0.2f * a;
  alpha[gid] = a;
  atomicMax(&menc[dnode * 4 + hh], encf(a));
}

// ---------- exp + atomic den / weighted-feature scatter ----------
__global__ void k_scatter(const float* __restrict__ alpha, const unsigned* __restrict__ menc,
                          const float* __restrict__ xl, const int* __restrict__ srcI,
                          const int* __restrict__ dstI, float* __restrict__ den,
                          float* __restrict__ outacc, int N, int E) {
  int item = blockIdx.x, c = threadIdx.x, hh = c >> 5;
  int sn, dn;
  if (item < E) { sn = srcI[item]; dn = dstI[item]; } else { sn = dn = item - E; }
  float m = decf(menc[dn * 4 + hh]);
  float ex = expf(alpha[item * 4 + hh] - m);
  atomicAdd(&outacc[dn * 128 + c], xl[sn * 128 + c] * ex);
  if (c < 4) {
    float ex2 = expf(alpha[item * 4 + c] - decf(menc[dn * 4 + c]));
    atomicAdd(&den[dn * 4 + c], ex2);
  }
}

// ---------- hc = out/den + bias; h = LN(relu(hc)+h) ----------
__global__ void k_norm(const float* __restrict__ outacc, const float* __restrict__ den,
                       const float* __restrict__ bias, const float* __restrict__ lns,
                       const float* __restrict__ lnb, float* __restrict__ h, int N) {
  __shared__ float buf[128];
  int n = blockIdx.x, c = threadIdx.x, hh = c >> 5;
  float v = outacc[n * 128 + c] / den[n * 4 + hh] + bias[c];
  v = fmaxf(v, 0.f) + h[n * 128 + c];
  buf[c] = v;
  __syncthreads();
  for (int s = 64; s > 0; s >>= 1) { if (c < s) buf[c] += buf[c + s]; __syncthreads(); }
  float mean = buf[0] * (1.f / 128.f);
  __syncthreads();
  float dv = v - mean;
  buf[c] = dv * dv;
  __syncthreads();
  for (int s = 64; s > 0; s >>= 1) { if (c < s) buf[c] += buf[c + s]; __syncthreads(); }
  float var = buf[0] * (1.f / 128.f);
  h[n * 128 + c] = dv * (1.0f / sqrtf(var + 1e-5f)) * lns[c] + lnb[c];
}

// ---------- onsite / coupling MLPs (128 -> 64 -> 1) ----------
__global__ void k_mlp(const float* __restrict__ h, const float* __restrict__ e,
                      const float* __restrict__ w1n, const float* __restrict__ b1n,
                      const float* __restrict__ w2n, const float* __restrict__ b2n,
                      const float* __restrict__ w1e, const float* __restrict__ b1e,
                      const float* __restrict__ w2e, const float* __restrict__ b2e,
                      float* __restrict__ onsite, float* __restrict__ coup, int N, int E) {
  int row = blockIdx.x, t = threadIdx.x;
  const float *vec, *w1, *b1, *w2; float b2v;
  if (row < N) { vec = h + (size_t)row * 128; w1 = w1n; b1 = b1n; w2 = w2n; b2v = b2n[0]; }
  else         { vec = e + (size_t)(row - N) * 128; w1 = w1e; b1 = b1e; w2 = w2e; b2v = b2e[0]; }
  float acc = b1[t];
  for (int k = 0; k < 128; ++k) acc += vec[k] * w1[k * 64 + t];
  acc = fmaxf(acc, 0.f) * w2[t];
#pragma unroll
  for (int off = 32; off; off >>= 1) acc += __shfl_down(acc, off);
  if (t == 0) {
    float r = acc + b2v;
    if (row < N) onsite[row] = r; else coup[row - N] = r;
  }
}

// ---------- dna mask + per-graph local index (single wave) ----------
__global__ void k_dna(const float* __restrict__ x, const int* __restrict__ batch,
                      int* __restrict__ dna, int* __restrict__ loc, int N, int B) {
  __shared__ int perB[64];
  __shared__ int beforeB[64];
  int l = threadIdx.x;
  perB[l] = 0;
  __syncthreads();
  int chunk = (N + 63) >> 6;
  int s0 = l * chunk, s1 = min(N, s0 + chunk);
  int cnt = 0;
  for (int n = s0; n < s1; ++n) {
    int mi = (x[n * 4 + 0] != 0.f || x[n * 4 + 1] != 0.f ||
              x[n * 4 + 2] != 0.f || x[n * 4 + 3] != 0.f) ? 1 : 0;
    dna[n] = mi;
    cnt += mi;
    if (mi) atomicAdd(&perB[batch[n]], 1);
  }
  __syncthreads();
  int pre = cnt;
#pragma unroll
  for (int off = 1; off < 64; off <<= 1) {
    int o = __shfl_up(pre, off);
    if (l >= off) pre += o;
  }
  int excl = pre - cnt;
  if (l == 0) {
    int run = 0;
    for (int g = 0; g < B; ++g) { beforeB[g] = run; run += perB[g]; }
  }
  __syncthreads();
  int run = excl;
  for (int n = s0; n < s1; ++n) {
    loc[n] = run - beforeB[batch[n]];
    run += dna[n];
  }
}

// ---------- H init (0 off-diag, 1e-6 diag) ----------
__global__ void k_hinit(float* __restrict__ H, int total) {
  int idx = blockIdx.x * 256 + threadIdx.x;
  if (idx >= total) return;
  int ij = idx & (HSZ * HSZ - 1);
  H[idx] = ((ij >> 7) == (ij & 127)) ? 1e-6f : 0.f;
}

// ---------- H scatter-add: onsite diag + symmetric coupling ----------
__global__ void k_hadd(const int* __restrict__ dna, const int* __restrict__ loc,
                       const int* __restrict__ batch, const int* __restrict__ srcI,
                       const int* __restrict__ dstI, const float* __restrict__ onsite,
                       const float* __restrict__ coup, float* __restrict__ H, int N, int E) {
  int item = blockIdx.x * 256 + threadIdx.x;
  if (item >= N + E) return;
  if (item < N) {
    if (dna[item]) atomicAdd(&H[batch[item] * (HSZ * HSZ) + loc[item] * (HSZ + 1)], onsite[item]);
  } else {
    int ei = item - N;
    int s = srcI[ei], d = dstI[ei];
    if (dna[s] && dna[d]) {
      float cv = coup[ei];
      int b = batch[s];
      atomicAdd(&H[b * (HSZ * HSZ) + loc[s] * HSZ + loc[d]], cv);
      atomicAdd(&H[b * (HSZ * HSZ) + loc[d] * HSZ + loc[s]], cv);
    }
  }
}

// ---------- NEGF: Gr = inv((E*I - H) + i*diag(g)) via complex in-place ----------
// Gauss-Jordan w/ partial pivoting. 512 threads/block, 4x8 complex tile/thread.
// waves_per_eu(8,8): pins the allocator budget to 512/8 = 64 VGPRs. gfx950 HW
// wave slots halve above 64 regs (m69 steps at 64/128/256): R6's 72-reg build
// ran 2 blocks/CU (Occupancy 18.5%, dur 1206us) vs R5's 64-reg 4 blocks/CU
// (33%, 890us). The fmaf ELIM (kept) cut VALU busy 516->458us. This round =
// R5 occupancy + R6 instruction count. Tripwire: WRITE_SIZE >> 3MB = RA spill.
// All per-thread state is named float4s -- NO local arrays (R1-R3: mid-end
// scratch demotion, 60 GB traffic).
#define CSEL4(V, I) ((I) == 0 ? (V).x : (I) == 1 ? (V).y : (I) == 2 ? (V).z : (V).w)

__device__ __forceinline__ unsigned packm(float re, float im, int row) {
  float m = re * re + im * im;
  return (__float_as_uint(m) & 0xFFFFFF80u) | (unsigned)row;
}

__global__ __attribute__((amdgpu_flat_work_group_size(512, 512), amdgpu_waves_per_eu(8, 8)))
void k_negf(
    const float* __restrict__ Hm, const float* __restrict__ GL, const float* __restrict__ GR,
    float* __restrict__ outT, float* __restrict__ outD) {
  int bid = blockIdx.x;
  int b = bid / NEGRID, eix = bid % NEGRID;
  float Ev = (float)(-3.0 + (6.0 / 99.0) * (double)eix);

  int tid = threadIdx.x;
  int tr = tid >> 4, tc = tid & 15;   // 32 row-groups x 16 col-groups
  int r0 = tr << 2, c0 = tc << 3;     // 4 rows x 8 cols per thread

  __shared__ float gl_s[HSZ], gr_s[HSZ], g_s[HSZ];
  __shared__ float2 fcol[2][HSZ];
  __shared__ unsigned pmag[2][HSZ];
  __shared__ float2 prow[144];        // 9*tc + j (j<8): conflict-free stride
  __shared__ int colrow[HSZ];         // colrow[k] = p
  __shared__ int rowk[HSZ];           // rowk[p] = k  (-1 = not yet pivoted)
  __shared__ float redbuf[16];

  if (tid < HSZ) {
    float a_ = GL[b * HSZ + tid], b_ = GR[b * HSZ + tid];
    gl_s[tid] = a_; gr_s[tid] = b_;
    g_s[tid] = 0.5f * (a_ + b_) + 1e-12f;
    rowk[tid] = -1;
  }
  __syncthreads();

  // W tile: rows r0..r0+3, cols c0..c0+7. A = cols c0..c0+3, B = c0+4..c0+7.
  float4 rA0, rB0, iA0, iB0, rA1, rB1, iA1, iB1;
  float4 rA2, rB2, iA2, iB2, rA3, rB3, iA3, iB3;
  const float* Hb = Hm + (size_t)b * HSZ * HSZ;
#define INIT8(RA, RB, IA, IB, MR) do { \
    int r_ = r0 + MR; \
    const float4 hA = *(const float4*)(Hb + r_ * HSZ + c0); \
    const float4 hB = *(const float4*)(Hb + r_ * HSZ + c0 + 4); \
    float gv = g_s[r_]; \
    RA.x = ((c0 + 0 == r_) ? Ev : 0.f) - hA.x;  RA.y = ((c0 + 1 == r_) ? Ev : 0.f) - hA.y; \
    RA.z = ((c0 + 2 == r_) ? Ev : 0.f) - hA.z;  RA.w = ((c0 + 3 == r_) ? Ev : 0.f) - hA.w; \
    RB.x = ((c0 + 4 == r_) ? Ev : 0.f) - hB.x;  RB.y = ((c0 + 5 == r_) ? Ev : 0.f) - hB.y; \
    RB.z = ((c0 + 6 == r_) ? Ev : 0.f) - hB.z;  RB.w = ((c0 + 7 == r_) ? Ev : 0.f) - hB.w; \
    IA.x = (c0 + 0 == r_) ? gv : 0.f;  IA.y = (c0 + 1 == r_) ? gv : 0.f; \
    IA.z = (c0 + 2 == r_) ? gv : 0.f;  IA.w = (c0 + 3 == r_) ? gv : 0.f; \
    IB.x = (c0 + 4 == r_) ? gv : 0.f;  IB.y = (c0 + 5 == r_) ? gv : 0.f; \
    IB.z = (c0 + 6 == r_) ? gv : 0.f;  IB.w = (c0 + 7 == r_) ? gv : 0.f; \
  } while (0)
  INIT8(rA0, rB0, iA0, iB0, 0);
  INIT8(rA1, rB1, iA1, iB1, 1);
  INIT8(rA2, rB2, iA2, iB2, 2);
  INIT8(rA3, rB3, iA3, iB3, 3);

  if (tc == 0) {  // stage column 0
    fcol[0][r0 + 0] = make_float2(rA0.x, iA0.x); pmag[0][r0 + 0] = packm(rA0.x, iA0.x, r0 + 0);
    fcol[0][r0 + 1] = make_float2(rA1.x, iA1.x); pmag[0][r0 + 1] = packm(rA1.x, iA1.x, r0 + 1);
    fcol[0][r0 + 2] = make_float2(rA2.x, iA2.x); pmag[0][r0 + 2] = packm(rA2.x, iA2.x, r0 + 2);
    fcol[0][r0 + 3] = make_float2(rA3.x, iA3.x); pmag[0][r0 + 3] = packm(rA3.x, iA3.x, r0 + 3);
  }
  __syncthreads();

  int lane = tid & 63;
  for (int k = 0; k < HSZ; ++k) {
    int par = k & 1;
    // --- packed per-wave argmax over 128 magnitudes (single umax chain) ---
    unsigned v1 = pmag[par][lane], v2 = pmag[par][lane + 64];
    unsigned vm = v1 > v2 ? v1 : v2;
#pragma unroll
    for (int off = 32; off; off >>= 1) {
      unsigned ov = __shfl_xor(vm, off);
      vm = ov > vm ? ov : vm;
    }
    int p = (int)(vm & 127u);
    float2 piv = fcol[par][p];
    float idn = 1.0f / (piv.x * piv.x + piv.y * piv.y);
    float dre = piv.x * idn, dim = -piv.y * idn;

    bool e0 = (c0 + 0 == k), e1 = (c0 + 1 == k), e2 = (c0 + 2 == k), e3 = (c0 + 3 == k);
    bool e4 = (c0 + 4 == k), e5 = (c0 + 5 == k), e6 = (c0 + 6 == k), e7 = (c0 + 7 == k);

    // --- pivot-row owners (one row-group): stage + scale ---
    if (tr == (p >> 2)) {
      int mrp = p & 3;
      float4 sA = mrp == 0 ? rA0 : mrp == 1 ? rA1 : mrp == 2 ? rA2 : rA3;
      float4 sB = mrp == 0 ? rB0 : mrp == 1 ? rB1 : mrp == 2 ? rB2 : rB3;
      float4 tA = mrp == 0 ? iA0 : mrp == 1 ? iA1 : mrp == 2 ? iA2 : iA3;
      float4 tB = mrp == 0 ? iB0 : mrp == 1 ? iB1 : mrp == 2 ? iB2 : iB3;
      prow[9 * tc + 0] = make_float2(sA.x, tA.x);
      prow[9 * tc + 1] = make_float2(sA.y, tA.y);
      prow[9 * tc + 2] = make_float2(sA.z, tA.z);
      prow[9 * tc + 3] = make_float2(sA.w, tA.w);
      prow[9 * tc + 4] = make_float2(sB.x, tB.x);
      prow[9 * tc + 5] = make_float2(sB.y, tB.y);
      prow[9 * tc + 6] = make_float2(sB.z, tB.z);
      prow[9 * tc + 7] = make_float2(sB.w, tB.w);
      float4 nA, nB, mA, mB;
      nA.x = fmaf(sA.x, dre, -(tA.x * dim)); mA.x = fmaf(sA.x, dim, tA.x * dre);
      nA.y = fmaf(sA.y, dre, -(tA.y * dim)); mA.y = fmaf(sA.y, dim, tA.y * dre);
      nA.z = fmaf(sA.z, dre, -(tA.z * dim)); mA.z = fmaf(sA.z, dim, tA.z * dre);
      nA.w = fmaf(sA.w, dre, -(tA.w * dim)); mA.w = fmaf(sA.w, dim, tA.w * dre);
      nB.x = fmaf(sB.x, dre, -(tB.x * dim)); mB.x = fmaf(sB.x, dim, tB.x * dre);
      nB.y = fmaf(sB.y, dre, -(tB.y * dim)); mB.y = fmaf(sB.y, dim, tB.y * dre);
      nB.z = fmaf(sB.z, dre, -(tB.z * dim)); mB.z = fmaf(sB.z, dim, tB.z * dre);
      nB.w = fmaf(sB.w, dre, -(tB.w * dim)); mB.w = fmaf(sB.w, dim, tB.w * dre);
      if (e0) { nA.x = dre; mA.x = dim; }
      if (e1) { nA.y = dre; mA.y = dim; }
      if (e2) { nA.z = dre; mA.z = dim; }
      if (e3) { nA.w = dre; mA.w = dim; }
      if (e4) { nB.x = dre; mB.x = dim; }
      if (e5) { nB.y = dre; mB.y = dim; }
      if (e6) { nB.z = dre; mB.z = dim; }
      if (e7) { nB.w = dre; mB.w = dim; }
      if (mrp == 0)      { rA0 = nA; iA0 = mA; rB0 = nB; iB0 = mB; }
      else if (mrp == 1) { rA1 = nA; iA1 = mA; rB1 = nB; iB1 = mB; }
      else if (mrp == 2) { rA2 = nA; iA2 = mA; rB2 = nB; iB2 = mB; }
      else               { rA3 = nA; iA3 = mA; rB3 = nB; iB3 = mB; }
      if (tc == 0) { colrow[k] = p; rowk[p] = k; }
    }
    __syncthreads();

    // --- eliminate all rows != p (4 FMA per complex element, forced) ---
    float2 q0 = prow[9 * tc + 0], q1 = prow[9 * tc + 1];
    float2 q2 = prow[9 * tc + 2], q3 = prow[9 * tc + 3];
    float2 q4 = prow[9 * tc + 4], q5 = prow[9 * tc + 5];
    float2 q6 = prow[9 * tc + 6], q7 = prow[9 * tc + 7];
#define CELIM(RE, IM, Q, EK) do { \
      float nx = fmaf(fi, Q.y, fmaf(-fr, Q.x, RE)); \
      float ny = fmaf(-fi, Q.x, fmaf(-fr, Q.y, IM)); \
      RE = EK ? -fr : nx; IM = EK ? -fi : ny; \
    } while (0)
#define ELIM8(RA, IA, RB, IB, MR) do { \
      int rr_ = r0 + MR; \
      if (rr_ != p) { \
        float2 f_ = fcol[par][rr_]; \
        float fr = fmaf(f_.x, dre, -(f_.y * dim)); \
        float fi = fmaf(f_.x, dim, f_.y * dre); \
        CELIM(RA.x, IA.x, q0, e0); \
        CELIM(RA.y, IA.y, q1, e1); \
        CELIM(RA.z, IA.z, q2, e2); \
        CELIM(RA.w, IA.w, q3, e3); \
        CELIM(RB.x, IB.x, q4, e4); \
        CELIM(RB.y, IB.y, q5, e5); \
        CELIM(RB.z, IB.z, q6, e6); \
        CELIM(RB.w, IB.w, q7, e7); \
      } \
    } while (0)
    ELIM8(rA0, iA0, rB0, iB0, 0);
    ELIM8(rA1, iA1, rB1, iB1, 1);
    ELIM8(rA2, iA2, rB2, iB2, 2);
    ELIM8(rA3, iA3, rB3, iB3, 3);

    // --- stage column k+1 into other parity buffer ---
    if (k < HSZ - 1) {
      int k2 = k + 1, par2 = par ^ 1;
      if (tc == (k2 >> 3)) {
        int mck = k2 & 7;
        float re_, im_;
#define STG8(RA, IA, RB, IB, MR) do { \
        re_ = (mck < 4) ? CSEL4(RA, mck) : CSEL4(RB, mck - 4); \
        im_ = (mck < 4) ? CSEL4(IA, mck) : CSEL4(IB, mck - 4); \
        fcol[par2][r0 + MR] = make_float2(re_, im_); \
        pmag[par2][r0 + MR] = (rowk[r0 + MR] >= 0) ? 0u : packm(re_, im_, r0 + MR); \
      } while (0)
        STG8(rA0, iA0, rB0, iB0, 0);
        STG8(rA1, iA1, rB1, iB1, 1);
        STG8(rA2, iA2, rB2, iB2, 2);
        STG8(rA3, iA3, rB3, iB3, 3);
      }
    }
    __syncthreads();
  }

  // stored W[i][j] = Gr[ rowk[i] ][ colrow[j] ]  (permutation absorbed here)
  int cc0 = colrow[c0 + 0], cc1 = colrow[c0 + 1], cc2 = colrow[c0 + 2], cc3 = colrow[c0 + 3];
  int cc4 = colrow[c0 + 4], cc5 = colrow[c0 + 5], cc6 = colrow[c0 + 6], cc7 = colrow[c0 + 7];
  float gw0 = gr_s[cc0], gw1 = gr_s[cc1], gw2 = gr_s[cc2], gw3 = gr_s[cc3];
  float gw4 = gr_s[cc4], gw5 = gr_s[cc5], gw6 = gr_s[cc6], gw7 = gr_s[cc7];
  float Tacc = 0.f, Dacc = 0.f;
#define ACC8(RA, IA, RB, IB, MR) do { \
    int rr_ = rowk[r0 + MR]; \
    float glv = gl_s[rr_]; \
    float g2; \
    g2 = RA.x * RA.x + IA.x * IA.x; Tacc += glv * gw0 * g2; if (rr_ == cc0) Dacc += IA.x; \
    g2 = RA.y * RA.y + IA.y * IA.y; Tacc += glv * gw1 * g2; if (rr_ == cc1) Dacc += IA.y; \
    g2 = RA.z * RA.z + IA.z * IA.z; Tacc += glv * gw2 * g2; if (rr_ == cc2) Dacc += IA.z; \
    g2 = RA.w * RA.w + IA.w * IA.w; Tacc += glv * gw3 * g2; if (rr_ == cc3) Dacc += IA.w; \
    g2 = RB.x * RB.x + IB.x * IB.x; Tacc += glv * gw4 * g2; if (rr_ == cc4) Dacc += IB.x; \
    g2 = RB.y * RB.y + IB.y * IB.y; Tacc += glv * gw5 * g2; if (rr_ == cc5) Dacc += IB.y; \
    g2 = RB.z * RB.z + IB.z * IB.z; Tacc += glv * gw6 * g2; if (rr_ == cc6) Dacc += IB.z; \
    g2 = RB.w * RB.w + IB.w * IB.w; Tacc += glv * gw7 * g2; if (rr_ == cc7) Dacc += IB.w; \
  } while (0)
  ACC8(rA0, iA0, rB0, iB0, 0);
  ACC8(rA1, iA1, rB1, iB1, 1);
  ACC8(rA2, iA2, rB2, iB2, 2);
  ACC8(rA3, iA3, rB3, iB3, 3);
#pragma unroll
  for (int off = 32; off; off >>= 1) {
    Tacc += __shfl_xor(Tacc, off);
    Dacc += __shfl_xor(Dacc, off);
  }
  int wv = tid >> 6;
  if (lane == 0) { redbuf[wv] = Tacc; redbuf[8 + wv] = Dacc; }
  __syncthreads();
  if (tid == 0) {
    float T = 0.f, D = 0.f;
    for (int w = 0; w < 8; ++w) { T += redbuf[w]; D += redbuf[8 + w]; }
    outT[bid] = log10f(fmaxf(T, 1e-16f));
    outD[bid] = log10f(fmaxf(-D * 0.31830988618379067f, 1e-16f));
  }
}

extern "C" void kernel_launch(void* const* d_in, const int* in_sizes, int n_in,
                              void* d_out, int out_size, void* d_ws, size_t ws_size,
                              hipStream_t stream) {
  const float* x     = (const float*)d_in[0];
  const int*   eidx  = (const int*)d_in[1];
  const float* eattr = (const float*)d_in[2];
  const int*   batch = (const int*)d_in[3];
  const float* GL    = (const float*)d_in[4];
  const float* GR    = (const float*)d_in[5];
  const float* node_w  = (const float*)d_in[6];
  const float* node_b  = (const float*)d_in[7];
  const float* edgep_w = (const float*)d_in[8];
  const float* edgep_b = (const float*)d_in[9];
  const float* gat_lin      = (const float*)d_in[10];
  const float* att_src      = (const float*)d_in[11];
  const float* att_dst      = (const float*)d_in[12];
  const float* gat_lin_edge = (const float*)d_in[13];
  const float* att_edge     = (const float*)d_in[14];
  const float* gat_bias     = (const float*)d_in[15];
  const float* ln_s = (const float*)d_in[16];
  const float* ln_b = (const float*)d_in[17];
  const float* on_w1 = (const float*)d_in[18];
  const float* on_b1 = (const float*)d_in[19];
  const float* on_w2 = (const float*)d_in[20];
  const float* on_b2 = (const float*)d_in[21];
  const float* cp_w1 = (const float*)d_in[22];
  const float* cp_b1 = (const float*)d_in[23];
  const float* cp_w2 = (const float*)d_in[24];
  const float* cp_b2 = (const float*)d_in[25];

  int N = in_sizes[0] / 4;
  int E = in_sizes[1] / 2;
  int B = in_sizes[4] / HSZ;
  const int* srcI = eidx;
  const int* dstI = eidx + E;

  float* ws = (float*)d_ws;
  size_t o = 0;
  float* h     = ws + o; o += (size_t)N * 128;
  float* ebuf  = ws + o; o += (size_t)E * 128;
  float* xl    = ws + o; o += (size_t)N * 128;
  float* ssrc  = ws + o; o += (size_t)N * 4;
  float* sdst  = ws + o; o += (size_t)N * 4;
  float* sedge = ws + o; o += (size_t)E * 4;
  float* smean = ws + o; o += 16;
  float* alpha = ws + o; o += (size_t)(E + N) * 4;
  unsigned* menc = (unsigned*)(ws + o); o += (size_t)N * 4;
  float* den    = ws + o; o += (size_t)N * 4;
  float* outacc = ws + o; o += (size_t)N * 128;
  float* onsite = ws + o; o += (size_t)((N + 3) & ~3);
  float* coup   = ws + o; o += (size_t)((E + 3) & ~3);
  int* dna = (int*)(ws + o); o += (size_t)((N + 3) & ~3);
  int* loc = (int*)(ws + o); o += (size_t)((N + 3) & ~3);

  float* out  = (float*)d_out;
  float* outT = out;
  float* outD = out + (size_t)B * NEGRID;
  float* outH = out + (size_t)2 * B * NEGRID;

  k_embed<<<N + E, 128, 0, stream>>>(x, eattr, node_w, node_b, edgep_w, edgep_b,
                                     h, ebuf, smean, N, E);
  for (int l = 0; l < 4; ++l) {
    k_gat_lin<<<N + E, 128, 0, stream>>>(
        h, ebuf, gat_lin + (size_t)l * 16384, gat_lin_edge + (size_t)l * 16384,
        att_src + l * 128, att_dst + l * 128, att_edge + l * 128,
        xl, ssrc, sdst, sedge, smean + l * 4, menc, den, outacc, N, E);
    int items = (E + N) * 4;
    k_alpha<<<(items + 255) / 256, 256, 0, stream>>>(
        ssrc, sdst, sedge, smean + l * 4, srcI, dstI, alpha, menc, N, E, 1.0f / (float)E);
    k_scatter<<<E + N, 128, 0, stream>>>(alpha, menc, xl, srcI, dstI, den, outacc, N, E);
    k_norm<<<N, 128, 0, stream>>>(outacc, den, gat_bias + l * 128,
                                  ln_s + l * 128, ln_b + l * 128, h, N);
  }
  k_mlp<<<N + E, 64, 0, stream>>>(h, ebuf, on_w1, on_b1, on_w2, on_b2,
                                  cp_w1, cp_b1, cp_w2, cp_b2, onsite, coup, N, E);
  k_dna<<<1, 64, 0, stream>>>(x, batch, dna, loc, N, B);
  int htot = B * HSZ * HSZ;
  k_hinit<<<(htot + 255) / 256, 256, 0, stream>>>(outH, htot);
  k_hadd<<<(N + E + 255) / 256, 256, 0, stream>>>(dna, loc, batch, srcI, dstI,
                                                  onsite, coup, outH, N, E);
  k_negf<<<B * NEGRID, 512, 0, stream>>>(outH, GL, GR, outT, outD);
}

// Round 8
// 1048.906 us; speedup vs baseline: 4.4400x; 4.4400x over previous
//
#include <hip/hip_runtime.h>

#define HSZ 128
#define NEGRID 100

// ---------- float <-> order-preserving uint (for atomic float max) ----------
__device__ __forceinline__ unsigned encf(float f) {
  unsigned i = __float_as_uint(f);
  return (i & 0x80000000u) ? ~i : (i | 0x80000000u);
}
__device__ __forceinline__ float decf(unsigned u) {
  return (u & 0x80000000u) ? __uint_as_float(u & 0x7fffffffu) : __uint_as_float(~u);
}

// ---------- h = x@node_w + node_b ; e = edge_attr@edgep_w + edgep_b ----------
__global__ void k_embed(const float* __restrict__ x, const float* __restrict__ ea,
                        const float* __restrict__ nw, const float* __restrict__ nb,
                        const float* __restrict__ ew, const float* __restrict__ eb,
                        float* __restrict__ h, float* __restrict__ e,
                        float* __restrict__ smean, int N, int E) {
  int row = blockIdx.x, c = threadIdx.x;
  if (row == 0 && c < 16) smean[c] = 0.f;
  if (row < N) {
    float acc = nb[c];
#pragma unroll
    for (int k = 0; k < 4; ++k) acc += x[row * 4 + k] * nw[k * 128 + c];
    h[row * 128 + c] = acc;
  } else {
    int ei = row - N;
    float acc = eb[c];
#pragma unroll
    for (int k = 0; k < 5; ++k) acc += ea[ei * 5 + k] * ew[k * 128 + c];
    e[ei * 128 + c] = acc;
  }
}

// ---------- per layer: xl = h@W (nodes), s_src/s_dst per node; s_edge per edge ----------
__global__ void k_gat_lin(const float* __restrict__ h, const float* __restrict__ e,
                          const float* __restrict__ W, const float* __restrict__ We,
                          const float* __restrict__ asrc, const float* __restrict__ adst,
                          const float* __restrict__ aedge,
                          float* __restrict__ xl, float* __restrict__ ssrc,
                          float* __restrict__ sdst, float* __restrict__ sedge,
                          float* __restrict__ smean4, unsigned* __restrict__ menc,
                          float* __restrict__ den, float* __restrict__ outacc,
                          int N, int E) {
  __shared__ float row_lds[128];
  __shared__ float red[128];
  __shared__ float red2[128];
  int row = blockIdx.x, c = threadIdx.x;
  const float* M;
  if (row < N) { row_lds[c] = h[row * 128 + c]; M = W; }
  else         { row_lds[c] = e[(row - N) * 128 + c]; M = We; }
  __syncthreads();
  float acc = 0.f;
  for (int k = 0; k < 128; ++k) acc += row_lds[k] * M[k * 128 + c];
  if (row < N) {
    xl[row * 128 + c] = acc;
    outacc[row * 128 + c] = 0.f;
    if (c < 4) { menc[row * 4 + c] = 0u; den[row * 4 + c] = 0.f; }
    red[c]  = acc * asrc[c];
    red2[c] = acc * adst[c];
    __syncthreads();
    if (c < 8) {
      int hh = c & 3;
      const float* b = (c < 4) ? red : red2;
      float s = 0.f;
      for (int t = 0; t < 32; ++t) s += b[hh * 32 + t];
      if (c < 4) ssrc[row * 4 + hh] = s; else sdst[row * 4 + hh] = s;
    }
  } else {
    int ei = row - N;
    red[c] = acc * aedge[c];
    __syncthreads();
    if (c < 4) {
      float s = 0.f;
      for (int t = 0; t < 32; ++t) s += red[c * 32 + t];
      sedge[ei * 4 + c] = s;
      atomicAdd(&smean4[c], s);
    }
  }
}

// ---------- alpha (leaky-relu) + atomic segment max over dst ----------
__global__ void k_alpha(const float* __restrict__ ssrc, const float* __restrict__ sdst,
                        const float* __restrict__ sedge, const float* __restrict__ smean4,
                        const int* __restrict__ srcI, const int* __restrict__ dstI,
                        float* __restrict__ alpha, unsigned* __restrict__ menc,
                        int N, int E, float invE) {
  int gid = blockIdx.x * 256 + threadIdx.x;
  if (gid >= (E + N) * 4) return;
  int item = gid >> 2, hh = gid & 3;
  float a; int dnode;
  if (item < E) {
    a = ssrc[srcI[item] * 4 + hh] + sdst[dstI[item] * 4 + hh] + sedge[item * 4 + hh];
    dnode = dstI[item];
  } else {
    int n = item - E;
    a = ssrc[n * 4 + hh] + sdst[n * 4 + hh] + smean4[hh] * invE;
    dnode = n;
  }
  a = (a > 0.f) ? a : 0.2f * a;
  alpha[gid] = a;
  atomicMax(&menc[dnode * 4 + hh], encf(a));
}

// ---------- exp + atomic den / weighted-feature scatter ----------
__global__ void k_scatter(const float* __restrict__ alpha, const unsigned* __restrict__ menc,
                          const float* __restrict__ xl, const int* __restrict__ srcI,
                          const int* __restrict__ dstI, float* __restrict__ den,
                          float* __restrict__ outacc, int N, int E) {
  int item = blockIdx.x, c = threadIdx.x, hh = c >> 5;
  int sn, dn;
  if (item < E) { sn = srcI[item]; dn = dstI[item]; } else { sn = dn = item - E; }
  float m = decf(menc[dn * 4 + hh]);
  float ex = expf(alpha[item * 4 + hh] - m);
  atomicAdd(&outacc[dn * 128 + c], xl[sn * 128 + c] * ex);
  if (c < 4) {
    float ex2 = expf(alpha[item * 4 + c] - decf(menc[dn * 4 + c]));
    atomicAdd(&den[dn * 4 + c], ex2);
  }
}

// ---------- hc = out/den + bias; h = LN(relu(hc)+h) ----------
__global__ void k_norm(const float* __restrict__ outacc, const float* __restrict__ den,
                       const float* __restrict__ bias, const float* __restrict__ lns,
                       const float* __restrict__ lnb, float* __restrict__ h, int N) {
  __shared__ float buf[128];
  int n = blockIdx.x, c = threadIdx.x, hh = c >> 5;
  float v = outacc[n * 128 + c] / den[n * 4 + hh] + bias[c];
  v = fmaxf(v, 0.f) + h[n * 128 + c];
  buf[c] = v;
  __syncthreads();
  for (int s = 64; s > 0; s >>= 1) { if (c < s) buf[c] += buf[c + s]; __syncthreads(); }
  float mean = buf[0] * (1.f / 128.f);
  __syncthreads();
  float dv = v - mean;
  buf[c] = dv * dv;
  __syncthreads();
  for (int s = 64; s > 0; s >>= 1) { if (c < s) buf[c] += buf[c + s]; __syncthreads(); }
  float var = buf[0] * (1.f / 128.f);
  h[n * 128 + c] = dv * (1.0f / sqrtf(var + 1e-5f)) * lns[c] + lnb[c];
}

// ---------- onsite / coupling MLPs (128 -> 64 -> 1) ----------
__global__ void k_mlp(const float* __restrict__ h, const float* __restrict__ e,
                      const float* __restrict__ w1n, const float* __restrict__ b1n,
                      const float* __restrict__ w2n, const float* __restrict__ b2n,
                      const float* __restrict__ w1e, const float* __restrict__ b1e,
                      const float* __restrict__ w2e, const float* __restrict__ b2e,
                      float* __restrict__ onsite, float* __restrict__ coup, int N, int E) {
  int row = blockIdx.x, t = threadIdx.x;
  const float *vec, *w1, *b1, *w2; float b2v;
  if (row < N) { vec = h + (size_t)row * 128; w1 = w1n; b1 = b1n; w2 = w2n; b2v = b2n[0]; }
  else         { vec = e + (size_t)(row - N) * 128; w1 = w1e; b1 = b1e; w2 = w2e; b2v = b2e[0]; }
  float acc = b1[t];
  for (int k = 0; k < 128; ++k) acc += vec[k] * w1[k * 64 + t];
  acc = fmaxf(acc, 0.f) * w2[t];
#pragma unroll
  for (int off = 32; off; off >>= 1) acc += __shfl_down(acc, off);
  if (t == 0) {
    float r = acc + b2v;
    if (row < N) onsite[row] = r; else coup[row - N] = r;
  }
}

// ---------- dna mask + per-graph local index (single wave) ----------
__global__ void k_dna(const float* __restrict__ x, const int* __restrict__ batch,
                      int* __restrict__ dna, int* __restrict__ loc, int N, int B) {
  __shared__ int perB[64];
  __shared__ int beforeB[64];
  int l = threadIdx.x;
  perB[l] = 0;
  __syncthreads();
  int chunk = (N + 63) >> 6;
  int s0 = l * chunk, s1 = min(N, s0 + chunk);
  int cnt = 0;
  for (int n = s0; n < s1; ++n) {
    int mi = (x[n * 4 + 0] != 0.f || x[n * 4 + 1] != 0.f ||
              x[n * 4 + 2] != 0.f || x[n * 4 + 3] != 0.f) ? 1 : 0;
    dna[n] = mi;
    cnt += mi;
    if (mi) atomicAdd(&perB[batch[n]], 1);
  }
  __syncthreads();
  int pre = cnt;
#pragma unroll
  for (int off = 1; off < 64; off <<= 1) {
    int o = __shfl_up(pre, off);
    if (l >= off) pre += o;
  }
  int excl = pre - cnt;
  if (l == 0) {
    int run = 0;
    for (int g = 0; g < B; ++g) { beforeB[g] = run; run += perB[g]; }
  }
  __syncthreads();
  int run = excl;
  for (int n = s0; n < s1; ++n) {
    loc[n] = run - beforeB[batch[n]];
    run += dna[n];
  }
}

// ---------- H init (0 off-diag, 1e-6 diag) ----------
__global__ void k_hinit(float* __restrict__ H, int total) {
  int idx = blockIdx.x * 256 + threadIdx.x;
  if (idx >= total) return;
  int ij = idx & (HSZ * HSZ - 1);
  H[idx] = ((ij >> 7) == (ij & 127)) ? 1e-6f : 0.f;
}

// ---------- H scatter-add: onsite diag + symmetric coupling ----------
__global__ void k_hadd(const int* __restrict__ dna, const int* __restrict__ loc,
                       const int* __restrict__ batch, const int* __restrict__ srcI,
                       const int* __restrict__ dstI, const float* __restrict__ onsite,
                       const float* __restrict__ coup, float* __restrict__ H, int N, int E) {
  int item = blockIdx.x * 256 + threadIdx.x;
  if (item >= N + E) return;
  if (item < N) {
    if (dna[item]) atomicAdd(&H[batch[item] * (HSZ * HSZ) + loc[item] * (HSZ + 1)], onsite[item]);
  } else {
    int ei = item - N;
    int s = srcI[ei], d = dstI[ei];
    if (dna[s] && dna[d]) {
      float cv = coup[ei];
      int b = batch[s];
      atomicAdd(&H[b * (HSZ * HSZ) + loc[s] * HSZ + loc[d]], cv);
      atomicAdd(&H[b * (HSZ * HSZ) + loc[d] * HSZ + loc[s]], cv);
    }
  }
}

// ---------- NEGF: Gr = inv((E*I - H) + i*diag(g)) via complex in-place ----------
// Gauss-Jordan w/ partial pivoting. 512 threads/block, 4x8 complex tile/thread.
// R4-R7 ladder: named-scalar tile (no local arrays; mid-end demotes arrays to
// scratch: 60 GB traffic) -> 2 blocks/CU -> stay at VGPR<=64 (wave slots halve
// above 64: R6's 72-reg build lost 2x occupancy; R7's waves_per_eu(8,8) budget
// pin below demand triggered catastrophic RA spill, 18 GB). This round: the
// pivot column needs NO special-casing in the eliminator -- stage prow[k] as
// (piv+1) so the generic update W[r][k] -= fr*(piv+1) = -fr exactly (fr*piv=f).
// Removes 64 cndmask + 8 compares/iter from the hot path and ~16 live bools.
// prow stride 10 (80 B, 16B-aligned) -> q loads are 4x ds_read_b128.
// Attr (4,4): budget 128, no catastrophic-spill mode; demand ~64 fits.
#define CSEL4(V, I) ((I) == 0 ? (V).x : (I) == 1 ? (V).y : (I) == 2 ? (V).z : (V).w)

__device__ __forceinline__ unsigned packm(float re, float im, int row) {
  float m = re * re + im * im;
  return (__float_as_uint(m) & 0xFFFFFF80u) | (unsigned)row;
}

__global__ __attribute__((amdgpu_flat_work_group_size(512, 512), amdgpu_waves_per_eu(4, 4)))
void k_negf(
    const float* __restrict__ Hm, const float* __restrict__ GL, const float* __restrict__ GR,
    float* __restrict__ outT, float* __restrict__ outD) {
  int bid = blockIdx.x;
  int b = bid / NEGRID, eix = bid % NEGRID;
  float Ev = (float)(-3.0 + (6.0 / 99.0) * (double)eix);

  int tid = threadIdx.x;
  int tr = tid >> 4, tc = tid & 15;   // 32 row-groups x 16 col-groups
  int r0 = tr << 2, c0 = tc << 3;     // 4 rows x 8 cols per thread

  __shared__ float gl_s[HSZ], gr_s[HSZ], g_s[HSZ];
  __shared__ float2 fcol[2][HSZ];
  __shared__ unsigned pmag[2][HSZ];
  __shared__ float2 prow[160];        // stride 10*tc: 16B-aligned, 2-way-max conflicts
  __shared__ int colrow[HSZ];         // colrow[k] = p
  __shared__ int rowk[HSZ];           // rowk[p] = k  (-1 = not yet pivoted)
  __shared__ float redbuf[16];

  if (tid < HSZ) {
    float a_ = GL[b * HSZ + tid], b_ = GR[b * HSZ + tid];
    gl_s[tid] = a_; gr_s[tid] = b_;
    g_s[tid] = 0.5f * (a_ + b_) + 1e-12f;
    rowk[tid] = -1;
  }
  __syncthreads();

  // W tile: rows r0..r0+3, cols c0..c0+7. A = cols c0..c0+3, B = c0+4..c0+7.
  float4 rA0, rB0, iA0, iB0, rA1, rB1, iA1, iB1;
  float4 rA2, rB2, iA2, iB2, rA3, rB3, iA3, iB3;
  const float* Hb = Hm + (size_t)b * HSZ * HSZ;
#define INIT8(RA, RB, IA, IB, MR) do { \
    int r_ = r0 + MR; \
    const float4 hA = *(const float4*)(Hb + r_ * HSZ + c0); \
    const float4 hB = *(const float4*)(Hb + r_ * HSZ + c0 + 4); \
    float gv = g_s[r_]; \
    RA.x = ((c0 + 0 == r_) ? Ev : 0.f) - hA.x;  RA.y = ((c0 + 1 == r_) ? Ev : 0.f) - hA.y; \
    RA.z = ((c0 + 2 == r_) ? Ev : 0.f) - hA.z;  RA.w = ((c0 + 3 == r_) ? Ev : 0.f) - hA.w; \
    RB.x = ((c0 + 4 == r_) ? Ev : 0.f) - hB.x;  RB.y = ((c0 + 5 == r_) ? Ev : 0.f) - hB.y; \
    RB.z = ((c0 + 6 == r_) ? Ev : 0.f) - hB.z;  RB.w = ((c0 + 7 == r_) ? Ev : 0.f) - hB.w; \
    IA.x = (c0 + 0 == r_) ? gv : 0.f;  IA.y = (c0 + 1 == r_) ? gv : 0.f; \
    IA.z = (c0 + 2 == r_) ? gv : 0.f;  IA.w = (c0 + 3 == r_) ? gv : 0.f; \
    IB.x = (c0 + 4 == r_) ? gv : 0.f;  IB.y = (c0 + 5 == r_) ? gv : 0.f; \
    IB.z = (c0 + 6 == r_) ? gv : 0.f;  IB.w = (c0 + 7 == r_) ? gv : 0.f; \
  } while (0)
  INIT8(rA0, rB0, iA0, iB0, 0);
  INIT8(rA1, rB1, iA1, iB1, 1);
  INIT8(rA2, rB2, iA2, iB2, 2);
  INIT8(rA3, rB3, iA3, iB3, 3);

  if (tc == 0) {  // stage column 0
    fcol[0][r0 + 0] = make_float2(rA0.x, iA0.x); pmag[0][r0 + 0] = packm(rA0.x, iA0.x, r0 + 0);
    fcol[0][r0 + 1] = make_float2(rA1.x, iA1.x); pmag[0][r0 + 1] = packm(rA1.x, iA1.x, r0 + 1);
    fcol[0][r0 + 2] = make_float2(rA2.x, iA2.x); pmag[0][r0 + 2] = packm(rA2.x, iA2.x, r0 + 2);
    fcol[0][r0 + 3] = make_float2(rA3.x, iA3.x); pmag[0][r0 + 3] = packm(rA3.x, iA3.x, r0 + 3);
  }
  __syncthreads();

  int lane = tid & 63;
  for (int k = 0; k < HSZ; ++k) {
    int par = k & 1;
    // --- packed per-wave argmax over 128 magnitudes (single umax chain) ---
    unsigned v1 = pmag[par][lane], v2 = pmag[par][lane + 64];
    unsigned vm = v1 > v2 ? v1 : v2;
#pragma unroll
    for (int off = 32; off; off >>= 1) {
      unsigned ov = __shfl_xor(vm, off);
      vm = ov > vm ? ov : vm;
    }
    int p = (int)(vm & 127u);
    float2 piv = fcol[par][p];
    float idn = 1.0f / (piv.x * piv.x + piv.y * piv.y);
    float dre = piv.x * idn, dim = -piv.y * idn;

    // --- pivot-row owners (one row-group): stage (w/ piv+1 at col k) + scale ---
    if (tr == (p >> 2)) {
      int mrp = p & 3;
      float4 sA = mrp == 0 ? rA0 : mrp == 1 ? rA1 : mrp == 2 ? rA2 : rA3;
      float4 sB = mrp == 0 ? rB0 : mrp == 1 ? rB1 : mrp == 2 ? rB2 : rB3;
      float4 tA = mrp == 0 ? iA0 : mrp == 1 ? iA1 : mrp == 2 ? iA2 : iA3;
      float4 tB = mrp == 0 ? iB0 : mrp == 1 ? iB1 : mrp == 2 ? iB2 : iB3;
      float4* pw = (float4*)&prow[10 * tc];
      pw[0] = make_float4(sA.x, tA.x, sA.y, tA.y);
      pw[1] = make_float4(sA.z, tA.z, sA.w, tA.w);
      pw[2] = make_float4(sB.x, tB.x, sB.y, tB.y);
      pw[3] = make_float4(sB.z, tB.z, sB.w, tB.w);
      bool e0 = (c0 + 0 == k), e1 = (c0 + 1 == k), e2 = (c0 + 2 == k), e3 = (c0 + 3 == k);
      bool e4 = (c0 + 4 == k), e5 = (c0 + 5 == k), e6 = (c0 + 6 == k), e7 = (c0 + 7 == k);
      if (tc == (k >> 3)) prow[10 * tc + (k & 7)] = make_float2(piv.x + 1.f, piv.y);
      float4 nA, nB, mA, mB;
      nA.x = sA.x * dre - tA.x * dim; mA.x = sA.x * dim + tA.x * dre;
      nA.y = sA.y * dre - tA.y * dim; mA.y = sA.y * dim + tA.y * dre;
      nA.z = sA.z * dre - tA.z * dim; mA.z = sA.z * dim + tA.z * dre;
      nA.w = sA.w * dre - tA.w * dim; mA.w = sA.w * dim + tA.w * dre;
      nB.x = sB.x * dre - tB.x * dim; mB.x = sB.x * dim + tB.x * dre;
      nB.y = sB.y * dre - tB.y * dim; mB.y = sB.y * dim + tB.y * dre;
      nB.z = sB.z * dre - tB.z * dim; mB.z = sB.z * dim + tB.z * dre;
      nB.w = sB.w * dre - tB.w * dim; mB.w = sB.w * dim + tB.w * dre;
      if (e0) { nA.x = dre; mA.x = dim; }
      if (e1) { nA.y = dre; mA.y = dim; }
      if (e2) { nA.z = dre; mA.z = dim; }
      if (e3) { nA.w = dre; mA.w = dim; }
      if (e4) { nB.x = dre; mB.x = dim; }
      if (e5) { nB.y = dre; mB.y = dim; }
      if (e6) { nB.z = dre; mB.z = dim; }
      if (e7) { nB.w = dre; mB.w = dim; }
      if (mrp == 0)      { rA0 = nA; iA0 = mA; rB0 = nB; iB0 = mB; }
      else if (mrp == 1) { rA1 = nA; iA1 = mA; rB1 = nB; iB1 = mB; }
      else if (mrp == 2) { rA2 = nA; iA2 = mA; rB2 = nB; iB2 = mB; }
      else               { rA3 = nA; iA3 = mA; rB3 = nB; iB3 = mB; }
      if (tc == 0) { colrow[k] = p; rowk[p] = k; }
    }
    __syncthreads();

    // --- eliminate all rows != p: generic update, NO column-k special case ---
    const float4* qp = (const float4*)&prow[10 * tc];
    float4 qa = qp[0], qb = qp[1], qc = qp[2], qd = qp[3];  // (q0,q1)(q2,q3)(q4,q5)(q6,q7)
    const float4* fcp = (const float4*)&fcol[par][r0];
    float4 fa = fcp[0], fb = fcp[1];  // rows r0..r0+1, r0+2..r0+3
#define CELIM(RE, IM, QX, QY) do { \
      RE = RE - (fr * QX - fi * QY); \
      IM = IM - (fr * QY + fi * QX); \
    } while (0)
#define ELIM8(RA, IA, RB, IB, FX, FY, MR) do { \
      if (r0 + MR != p) { \
        float fr = FX * dre - FY * dim; \
        float fi = FX * dim + FY * dre; \
        CELIM(RA.x, IA.x, qa.x, qa.y); \
        CELIM(RA.y, IA.y, qa.z, qa.w); \
        CELIM(RA.z, IA.z, qb.x, qb.y); \
        CELIM(RA.w, IA.w, qb.z, qb.w); \
        CELIM(RB.x, IB.x, qc.x, qc.y); \
        CELIM(RB.y, IB.y, qc.z, qc.w); \
        CELIM(RB.z, IB.z, qd.x, qd.y); \
        CELIM(RB.w, IB.w, qd.z, qd.w); \
      } \
    } while (0)
    ELIM8(rA0, iA0, rB0, iB0, fa.x, fa.y, 0);
    ELIM8(rA1, iA1, rB1, iB1, fa.z, fa.w, 1);
    ELIM8(rA2, iA2, rB2, iB2, fb.x, fb.y, 2);
    ELIM8(rA3, iA3, rB3, iB3, fb.z, fb.w, 3);

    // --- stage column k+1 into other parity buffer ---
    if (k < HSZ - 1) {
      int k2 = k + 1, par2 = par ^ 1;
      if (tc == (k2 >> 3)) {
        int mck = k2 & 7;
        float re_, im_;
#define STG8(RA, IA, RB, IB, MR) do { \
        re_ = (mck < 4) ? CSEL4(RA, mck) : CSEL4(RB, mck - 4); \
        im_ = (mck < 4) ? CSEL4(IA, mck) : CSEL4(IB, mck - 4); \
        fcol[par2][r0 + MR] = make_float2(re_, im_); \
        pmag[par2][r0 + MR] = (rowk[r0 + MR] >= 0) ? 0u : packm(re_, im_, r0 + MR); \
      } while (0)
        STG8(rA0, iA0, rB0, iB0, 0);
        STG8(rA1, iA1, rB1, iB1, 1);
        STG8(rA2, iA2, rB2, iB2, 2);
        STG8(rA3, iA3, rB3, iB3, 3);
      }
    }
    __syncthreads();
  }

  // stored W[i][j] = Gr[ rowk[i] ][ colrow[j] ]  (permutation absorbed here)
  int cc0 = colrow[c0 + 0], cc1 = colrow[c0 + 1], cc2 = colrow[c0 + 2], cc3 = colrow[c0 + 3];
  int cc4 = colrow[c0 + 4], cc5 = colrow[c0 + 5], cc6 = colrow[c0 + 6], cc7 = colrow[c0 + 7];
  float gw0 = gr_s[cc0], gw1 = gr_s[cc1], gw2 = gr_s[cc2], gw3 = gr_s[cc3];
  float gw4 = gr_s[cc4], gw5 = gr_s[cc5], gw6 = gr_s[cc6], gw7 = gr_s[cc7];
  float Tacc = 0.f, Dacc = 0.f;
#define ACC8(RA, IA, RB, IB, MR) do { \
    int rr_ = rowk[r0 + MR]; \
    float glv = gl_s[rr_]; \
    float g2; \
    g2 = RA.x * RA.x + IA.x * IA.x; Tacc += glv * gw0 * g2; if (rr_ == cc0) Dacc += IA.x; \
    g2 = RA.y * RA.y + IA.y * IA.y; Tacc += glv * gw1 * g2; if (rr_ == cc1) Dacc += IA.y; \
    g2 = RA.z * RA.z + IA.z * IA.z; Tacc += glv * gw2 * g2; if (rr_ == cc2) Dacc += IA.z; \
    g2 = RA.w * RA.w + IA.w * IA.w; Tacc += glv * gw3 * g2; if (rr_ == cc3) Dacc += IA.w; \
    g2 = RB.x * RB.x + IB.x * IB.x; Tacc += glv * gw4 * g2; if (rr_ == cc4) Dacc += IB.x; \
    g2 = RB.y * RB.y + IB.y * IB.y; Tacc += glv * gw5 * g2; if (rr_ == cc5) Dacc += IB.y; \
    g2 = RB.z * RB.z + IB.z * IB.z; Tacc += glv * gw6 * g2; if (rr_ == cc6) Dacc += IB.z; \
    g2 = RB.w * RB.w + IB.w * IB.w; Tacc += glv * gw7 * g2; if (rr_ == cc7) Dacc += IB.w; \
  } while (0)
  ACC8(rA0, iA0, rB0, iB0, 0);
  ACC8(rA1, iA1, rB1, iB1, 1);
  ACC8(rA2, iA2, rB2, iB2, 2);
  ACC8(rA3, iA3, rB3, iB3, 3);
#pragma unroll
  for (int off = 32; off; off >>= 1) {
    Tacc += __shfl_xor(Tacc, off);
    Dacc += __shfl_xor(Dacc, off);
  }
  int wv = tid >> 6;
  if (lane == 0) { redbuf[wv] = Tacc; redbuf[8 + wv] = Dacc; }
  __syncthreads();
  if (tid == 0) {
    float T = 0.f, D = 0.f;
    for (int w = 0; w < 8; ++w) { T += redbuf[w]; D += redbuf[8 + w]; }
    outT[bid] = log10f(fmaxf(T, 1e-16f));
    outD[bid] = log10f(fmaxf(-D * 0.31830988618379067f, 1e-16f));
  }
}

extern "C" void kernel_launch(void* const* d_in, const int* in_sizes, int n_in,
                              void* d_out, int out_size, void* d_ws, size_t ws_size,
                              hipStream_t stream) {
  const float* x     = (const float*)d_in[0];
  const int*   eidx  = (const int*)d_in[1];
  const float* eattr = (const float*)d_in[2];
  const int*   batch = (const int*)d_in[3];
  const float* GL    = (const float*)d_in[4];
  const float* GR    = (const float*)d_in[5];
  const float* node_w  = (const float*)d_in[6];
  const float* node_b  = (const float*)d_in[7];
  const float* edgep_w = (const float*)d_in[8];
  const float* edgep_b = (const float*)d_in[9];
  const float* gat_lin      = (const float*)d_in[10];
  const float* att_src      = (const float*)d_in[11];
  const float* att_dst      = (const float*)d_in[12];
  const float* gat_lin_edge = (const float*)d_in[13];
  const float* att_edge     = (const float*)d_in[14];
  const float* gat_bias     = (const float*)d_in[15];
  const float* ln_s = (const float*)d_in[16];
  const float* ln_b = (const float*)d_in[17];
  const float* on_w1 = (const float*)d_in[18];
  const float* on_b1 = (const float*)d_in[19];
  const float* on_w2 = (const float*)d_in[20];
  const float* on_b2 = (const float*)d_in[21];
  const float* cp_w1 = (const float*)d_in[22];
  const float* cp_b1 = (const float*)d_in[23];
  const float* cp_w2 = (const float*)d_in[24];
  const float* cp_b2 = (const float*)d_in[25];

  int N = in_sizes[0] / 4;
  int E = in_sizes[1] / 2;
  int B = in_sizes[4] / HSZ;
  const int* srcI = eidx;
  const int* dstI = eidx + E;

  float* ws = (float*)d_ws;
  size_t o = 0;
  float* h     = ws + o; o += (size_t)N * 128;
  float* ebuf  = ws + o; o += (size_t)E * 128;
  float* xl    = ws + o; o += (size_t)N * 128;
  float* ssrc  = ws + o; o += (size_t)N * 4;
  float* sdst  = ws + o; o += (size_t)N * 4;
  float* sedge = ws + o; o += (size_t)E * 4;
  float* smean = ws + o; o += 16;
  float* alpha = ws + o; o += (size_t)(E + N) * 4;
  unsigned* menc = (unsigned*)(ws + o); o += (size_t)N * 4;
  float* den    = ws + o; o += (size_t)N * 4;
  float* outacc = ws + o; o += (size_t)N * 128;
  float* onsite = ws + o; o += (size_t)((N + 3) & ~3);
  float* coup   = ws + o; o += (size_t)((E + 3) & ~3);
  int* dna = (int*)(ws + o); o += (size_t)((N + 3) & ~3);
  int* loc = (int*)(ws + o); o += (size_t)((N + 3) & ~3);

  float* out  = (float*)d_out;
  float* outT = out;
  float* outD = out + (size_t)B * NEGRID;
  float* outH = out + (size_t)2 * B * NEGRID;

  k_embed<<<N + E, 128, 0, stream>>>(x, eattr, node_w, node_b, edgep_w, edgep_b,
                                     h, ebuf, smean, N, E);
  for (int l = 0; l < 4; ++l) {
    k_gat_lin<<<N + E, 128, 0, stream>>>(
        h, ebuf, gat_lin + (size_t)l * 16384, gat_lin_edge + (size_t)l * 16384,
        att_src + l * 128, att_dst + l * 128, att_edge + l * 128,
        xl, ssrc, sdst, sedge, smean + l * 4, menc, den, outacc, N, E);
    int items = (E + N) * 4;
    k_alpha<<<(items + 255) / 256, 256, 0, stream>>>(
        ssrc, sdst, sedge, smean + l * 4, srcI, dstI, alpha, menc, N, E, 1.0f / (float)E);
    k_scatter<<<E + N, 128, 0, stream>>>(alpha, menc, xl, srcI, dstI, den, outacc, N, E);
    k_norm<<<N, 128, 0, stream>>>(outacc, den, gat_bias + l * 128,
                                  ln_s + l * 128, ln_b + l * 128, h, N);
  }
  k_mlp<<<N + E, 64, 0, stream>>>(h, ebuf, on_w1, on_b1, on_w2, on_b2,
                                  cp_w1, cp_b1, cp_w2, cp_b2, onsite, coup, N, E);
  k_dna<<<1, 64, 0, stream>>>(x, batch, dna, loc, N, B);
  int htot = B * HSZ * HSZ;
  k_hinit<<<(htot + 255) / 256, 256, 0, stream>>>(outH, htot);
  k_hadd<<<(N + E + 255) / 256, 256, 0, stream>>>(dna, loc, batch, srcI, dstI,
                                                  onsite, coup, outH, N, E);
  k_negf<<<B * NEGRID, 512, 0, stream>>>(outH, GL, GR, outT, outD);
}